// Round 1
// baseline (2977.944 us; speedup 1.0000x reference)
//
#include <hip/hip_runtime.h>
#include <hip/hip_fp16.h>

// Problem constants
#define BB 32
#define LL 256
#define TT 128
#define DD 256

#define C2X 2.8853900817779268f   // 2*log2(e)
#define LOG2E 1.4426950408889634f

// workspace layout (bytes)
#define WYS_OFF   0u                       // half [32][256][256], pre-scaled by 2*log2e
#define PREM_OFF  4194304u                 // half [32][256][256]
#define HWH_OFF   8388608u                 // float [128][32][256]
#define WR_OFF    12582912u                // half [256][256]
#define WT_OFF    12714. // (placeholder fixed below)
#undef WT_OFF
#define WT_OFF    12713984u                // half [256][256]

// LDS layout (dynamic)
#define LDS_WY    0u        // 131072 bytes, fp16 swizzled
#define LDS_S     131072u   // 256 f32
#define LDS_WA    132096u   // 256 f32
#define LDS_Z     133120u   // 256 f32
#define LDS_AL    134144u   // 256 f32
#define LDS_R     135168u   // 256 f32
#define LDS_PART  136192u   // 1024 f32
#define LDS_RED   140288u   // 16 f32
#define LDS_TOTAL 140352u

// ---------------- prep: GEMMs ----------------
// MODE 0: WY rows (b,l): out_h[r*256+d] = half( (prem_row . w_y[:,d]) * 2log2e ), 8192 rows
// MODE 1: HWh rows (t,b): out_f[r*256+d] = hyp_row . w_h[:,d], 4096 rows
template<int MODE>
__global__ __launch_bounds__(256) void prep_gemm(const float* __restrict__ x,
                                                 const float* __restrict__ w,
                                                 float* __restrict__ outf,
                                                 __half* __restrict__ outh) {
    __shared__ float At[8][256];
    const int d = threadIdx.x;
    const int row0 = blockIdx.x * 8;
    for (int rr = 0; rr < 8; ++rr) {
        int r = row0 + rr;
        const float* src;
        if (MODE == 0) { int b = r >> 8, l = r & 255; src = x + (size_t)(b * 384 + l) * 256; }
        else           { int t = r >> 5, b = r & 31;  src = x + (size_t)(b * 384 + 256 + t) * 256; }
        At[rr][d] = src[d];
    }
    __syncthreads();
    float acc[8] = {0.f,0.f,0.f,0.f,0.f,0.f,0.f,0.f};
    for (int k = 0; k < 256; k += 4) {
        float w0 = w[(size_t)(k + 0) * 256 + d];
        float w1 = w[(size_t)(k + 1) * 256 + d];
        float w2 = w[(size_t)(k + 2) * 256 + d];
        float w3 = w[(size_t)(k + 3) * 256 + d];
#pragma unroll
        for (int rr = 0; rr < 8; ++rr) {
            const float4 a = *(const float4*)&At[rr][k];
            float t0 = fmaf(a.x, w0, acc[rr]);
            t0 = fmaf(a.y, w1, t0);
            t0 = fmaf(a.z, w2, t0);
            acc[rr] = fmaf(a.w, w3, t0);
        }
    }
    for (int rr = 0; rr < 8; ++rr) {
        int r = row0 + rr;
        if (MODE == 0) outh[(size_t)r * 256 + d] = __float2half(acc[rr] * C2X);
        else           outf[(size_t)r * 256 + d] = acc[rr];
    }
}

// ---------------- prep: fp16 conversions ----------------
// quads: premise 524288, w_r 16384, w_t 16384  => 557056 total, grid 2176*256
__global__ __launch_bounds__(256) void prep_cvt(const float* __restrict__ x,
                                                const float* __restrict__ wr,
                                                const float* __restrict__ wt,
                                                __half* __restrict__ prem_h,
                                                __half* __restrict__ wr_h,
                                                __half* __restrict__ wt_h) {
    int i = blockIdx.x * 256 + threadIdx.x;
    float4 v;
    __half* dst;
    int e;
    if (i < 524288) {
        e = i * 4;
        int b = e >> 16;                  // e / 65536
        v = *(const float4*)(x + (size_t)e + (size_t)b * 32768); // (b*384+l)*256+d
        dst = prem_h + e;
    } else if (i < 524288 + 16384) {
        e = (i - 524288) * 4;
        v = *(const float4*)(wr + e);
        dst = wr_h + e;
    } else if (i < 557056) {
        e = (i - 540672) * 4;
        v = *(const float4*)(wt + e);
        dst = wt_h + e;
    } else {
        return;
    }
    __half h[4] = { __float2half(v.x), __float2half(v.y), __float2half(v.z), __float2half(v.w) };
    *(uint2*)dst = *(const uint2*)h;
}

// ---------------- main persistent recurrence ----------------
__global__ __launch_bounds__(1024) void wbw_main(const __half* __restrict__ wys,
                                                 const __half* __restrict__ prem,
                                                 const float* __restrict__ hwh,
                                                 const __half* __restrict__ wrh,
                                                 const __half* __restrict__ wth,
                                                 const float* __restrict__ walpha,
                                                 float* __restrict__ out) {
    extern __shared__ char lds[];
    char*  wy_b  = lds + LDS_WY;
    float* s_sh  = (float*)(lds + LDS_S);
    float* wa_sh = (float*)(lds + LDS_WA);
    float* al_sh = (float*)(lds + LDS_AL);
    float* rsh   = (float*)(lds + LDS_R);
    float* part  = (float*)(lds + LDS_PART);
    float* red   = (float*)(lds + LDS_RED);

    const int tid = threadIdx.x;
    const int b   = blockIdx.x;
    const int dl  = tid & 255;   // d or l depending on phase
    const int q   = tid >> 8;    // 0..3

    // ---- stage WY (fp16, pre-scaled) into LDS with XOR swizzle ----
    {
        const uint4* g = (const uint4*)(wys + (size_t)b * 65536);
#pragma unroll
        for (int it = 0; it < 8; ++it) {
            int q16 = it * 1024 + tid;        // uint4 index (8 halves)
            uint4 v = g[q16];
            unsigned e  = (unsigned)q16 * 8u; // element index
            unsigned l  = e >> 8;
            unsigned bo = (e * 2u) ^ ((l & 7u) << 4);
            *(uint4*)(wy_b + bo) = v;
        }
        if (tid < 256) { wa_sh[tid] = walpha[tid]; rsh[tid] = 0.f; }
    }
    __syncthreads();

    for (int t = 0; t < TT; ++t) {
        // ---- Phase A: partials of r @ w_r ----
        {
            const int d = dl;
            const __half* wcol = wrh + d;
            const int k0 = q * 64;
            float acc = 0.f;
            for (int i = 0; i < 64; i += 8) {
                const float4 r0 = *(const float4*)&rsh[k0 + i];
                const float4 r1 = *(const float4*)&rsh[k0 + i + 4];
                float wv[8];
#pragma unroll
                for (int j = 0; j < 8; ++j) wv[j] = __half2float(wcol[(size_t)(k0 + i + j) * 256]);
                acc = fmaf(r0.x, wv[0], acc); acc = fmaf(r0.y, wv[1], acc);
                acc = fmaf(r0.z, wv[2], acc); acc = fmaf(r0.w, wv[3], acc);
                acc = fmaf(r1.x, wv[4], acc); acc = fmaf(r1.y, wv[5], acc);
                acc = fmaf(r1.z, wv[6], acc); acc = fmaf(r1.w, wv[7], acc);
            }
            part[q * 256 + d] = acc;
        }
        __syncthreads();
        if (tid < 256) {
            const int d = tid;
            float hw = hwh[((size_t)t * 32 + b) * 256 + d];
            float s  = hw + part[d] + part[256 + d] + part[512 + d] + part[768 + d];
            s_sh[d]  = s * C2X;   // pre-scale for exp2
        }
        __syncthreads();

        // ---- Phase B: T[l] = sum_d wa[d] / (exp2(WY'+s') + 1) ----
        {
            const int l = dl;
            const unsigned base = (unsigned)l * 512u + (unsigned)q * 128u;
            const unsigned swz  = ((unsigned)l & 7u) << 4;
            float acc0 = 0.f, acc1 = 0.f;
#pragma unroll
            for (int i8 = 0; i8 < 8; ++i8) {
                unsigned bo = (base + (unsigned)i8 * 16u) ^ swz;
                const uint4 pk = *(const uint4*)(wy_b + bo);
                const float4 sv0 = *(const float4*)&s_sh[q * 64 + i8 * 8];
                const float4 sv1 = *(const float4*)&s_sh[q * 64 + i8 * 8 + 4];
                const float4 wa0 = *(const float4*)&wa_sh[q * 64 + i8 * 8];
                const float4 wa1 = *(const float4*)&wa_sh[q * 64 + i8 * 8 + 4];
                const __half2* h2 = (const __half2*)&pk;
                const float2 f0 = __half22float2(h2[0]);
                const float2 f1 = __half22float2(h2[1]);
                const float2 f2 = __half22float2(h2[2]);
                const float2 f3 = __half22float2(h2[3]);
                float x, eu;
                x = f0.x + sv0.x; eu = __builtin_amdgcn_rcpf(__builtin_amdgcn_exp2f(x) + 1.f); acc0 = fmaf(wa0.x, eu, acc0);
                x = f0.y + sv0.y; eu = __builtin_amdgcn_rcpf(__builtin_amdgcn_exp2f(x) + 1.f); acc1 = fmaf(wa0.y, eu, acc1);
                x = f1.x + sv0.z; eu = __builtin_amdgcn_rcpf(__builtin_amdgcn_exp2f(x) + 1.f); acc0 = fmaf(wa0.z, eu, acc0);
                x = f1.y + sv0.w; eu = __builtin_amdgcn_rcpf(__builtin_amdgcn_exp2f(x) + 1.f); acc1 = fmaf(wa0.w, eu, acc1);
                x = f2.x + sv1.x; eu = __builtin_amdgcn_rcpf(__builtin_amdgcn_exp2f(x) + 1.f); acc0 = fmaf(wa1.x, eu, acc0);
                x = f2.y + sv1.y; eu = __builtin_amdgcn_rcpf(__builtin_amdgcn_exp2f(x) + 1.f); acc1 = fmaf(wa1.y, eu, acc1);
                x = f3.x + sv1.z; eu = __builtin_amdgcn_rcpf(__builtin_amdgcn_exp2f(x) + 1.f); acc0 = fmaf(wa1.z, eu, acc0);
                x = f3.y + sv1.w; eu = __builtin_amdgcn_rcpf(__builtin_amdgcn_exp2f(x) + 1.f); acc1 = fmaf(wa1.w, eu, acc1);
            }
            part[q * 256 + dl] = acc0 + acc1;
        }
        __syncthreads();

        // ---- softmax over l (scores z = -2*T; additive const dropped) ----
        float z_reg = 0.f, e_reg = 0.f;
        if (tid < 256) {
            const int l = tid;
            float T = part[l] + part[256 + l] + part[512 + l] + part[768 + l];
            z_reg = -2.f * T;
            float v = z_reg;
#pragma unroll
            for (int off = 32; off; off >>= 1) v = fmaxf(v, __shfl_xor(v, off, 64));
            if ((tid & 63) == 0) red[tid >> 6] = v;
        }
        __syncthreads();
        if (tid < 256) {
            float m = fmaxf(fmaxf(red[0], red[1]), fmaxf(red[2], red[3]));
            e_reg = __builtin_amdgcn_exp2f((z_reg - m) * LOG2E);
            float v = e_reg;
#pragma unroll
            for (int off = 32; off; off >>= 1) v += __shfl_xor(v, off, 64);
            if ((tid & 63) == 0) red[4 + (tid >> 6)] = v;
        }
        __syncthreads();
        if (tid < 256) {
            float denom = red[4] + red[5] + red[6] + red[7];
            al_sh[tid] = e_reg * __builtin_amdgcn_rcpf(denom);
        }
        __syncthreads();

        // ---- Phase D: partials of alpha@premise + r@w_t ----
        {
            const int d = dl;
            const __half* pcol = prem + (size_t)b * 65536 + d;
            const __half* wcol = wth + d;
            const int l0 = q * 64;
            float acc = 0.f;
            for (int i = 0; i < 64; i += 4) {
                const float4 al = *(const float4*)&al_sh[l0 + i];
                const float4 rv = *(const float4*)&rsh[l0 + i];
                float pv[4], wv[4];
#pragma unroll
                for (int j = 0; j < 4; ++j) {
                    pv[j] = __half2float(pcol[(size_t)(l0 + i + j) * 256]);
                    wv[j] = __half2float(wcol[(size_t)(l0 + i + j) * 256]);
                }
                acc = fmaf(al.x, pv[0], acc); acc = fmaf(rv.x, wv[0], acc);
                acc = fmaf(al.y, pv[1], acc); acc = fmaf(rv.y, wv[1], acc);
                acc = fmaf(al.z, pv[2], acc); acc = fmaf(rv.z, wv[2], acc);
                acc = fmaf(al.w, pv[3], acc); acc = fmaf(rv.w, wv[3], acc);
            }
            part[q * 256 + d] = acc;
        }
        __syncthreads();
        if (tid < 256) {
            const int d = tid;
            float rn = part[d] + part[256 + d] + part[512 + d] + part[768 + d];
            rsh[d] = rn;
            out[((size_t)b * 128 + t) * 256 + d] = rn;
        }
        __syncthreads();
    }
}

extern "C" void kernel_launch(void* const* d_in, const int* in_sizes, int n_in,
                              void* d_out, int out_size, void* d_ws, size_t ws_size,
                              hipStream_t stream) {
    const float* x   = (const float*)d_in[0];
    const float* wy  = (const float*)d_in[1];
    const float* wh  = (const float*)d_in[2];
    const float* wr  = (const float*)d_in[3];
    const float* wal = (const float*)d_in[4];
    const float* wt  = (const float*)d_in[5];

    char* ws = (char*)d_ws;
    __half* wys    = (__half*)(ws + WYS_OFF);
    __half* prem_h = (__half*)(ws + PREM_OFF);
    float*  hwh    = (float*)(ws + HWH_OFF);
    __half* wr_h   = (__half*)(ws + WR_OFF);
    __half* wt_h   = (__half*)(ws + WT_OFF);

    hipFuncSetAttribute((const void*)wbw_main,
                        hipFuncAttributeMaxDynamicSharedMemorySize, (int)LDS_TOTAL);

    prep_gemm<0><<<1024, 256, 0, stream>>>(x, wy, nullptr, wys);
    prep_gemm<1><<<512, 256, 0, stream>>>(x, wh, hwh, nullptr);
    prep_cvt<<<2176, 256, 0, stream>>>(x, wr, wt, prem_h, wr_h, wt_h);
    wbw_main<<<32, 1024, LDS_TOTAL, stream>>>(wys, prem_h, hwh, wr_h, wt_h, wal, (float*)d_out);
}